// Round 8
// baseline (1852.538 us; speedup 1.0000x reference)
//
#include <hip/hip_runtime.h>
#include <hip/hip_bf16.h>
#include <cstddef>
#include <cstdint>

#define LSEQ   4096
#define NB     2
#define DMODEL 1024
#define DINNER 2048
#define DSTATE 16
#define DTRANK 64
#define NPROJ  96
#define MROWS  (NB * LSEQ)
#define WS_REQUIRED 229638144ull

typedef __attribute__((ext_vector_type(8))) short bf16x8_t;
typedef __attribute__((ext_vector_type(4))) float f32x4_t;

__device__ __forceinline__ float silu_f(float v) { return v / (1.f + __expf(-v)); }

__device__ __forceinline__ ushort f2bf(float f) {
  uint u = __builtin_bit_cast(uint, f);
  u += 0x7fff + ((u >> 16) & 1);          // round-to-nearest-even
  return (ushort)(u >> 16);
}
__device__ __forceinline__ float bf2f(ushort h) {
  uint u = ((uint)h) << 16;
  return __builtin_bit_cast(float, u);
}
__device__ __forceinline__ void split4(const float* f, ushort4* h, ushort4* l) {
  ushort* hp = (ushort*)h; ushort* lp = (ushort*)l;
  #pragma unroll
  for (int j = 0; j < 4; ++j) {
    hp[j] = f2bf(f[j]);
    lp[j] = f2bf(f[j] - bf2f(hp[j]));
  }
}

// ---------------- ws-too-small sentinel ----------------
__global__ void poison_kernel(float* __restrict__ out) {
  out[blockIdx.x * 256 + threadIdx.x] = 1e30f;
}

// ---------------- LayerNorm over last dim (1024), output split bf16 planes --
__global__ __launch_bounds__(256) void ln_split_kernel(
    const float* __restrict__ x, const float* __restrict__ w,
    const float* __restrict__ b, ushort* __restrict__ xnhi,
    ushort* __restrict__ xnlo)
{
  int row = blockIdx.x;
  int tid = threadIdx.x;
  const float4* xr = (const float4*)(x + (size_t)row * DMODEL);
  float4 v = xr[tid];
  float s  = v.x + v.y + v.z + v.w;
  float s2 = v.x*v.x + v.y*v.y + v.z*v.z + v.w*v.w;
  #pragma unroll
  for (int o = 32; o > 0; o >>= 1) {
    s  += __shfl_down(s, o);
    s2 += __shfl_down(s2, o);
  }
  __shared__ float red[8];
  int wv = tid >> 6;
  if ((tid & 63) == 0) { red[wv*2] = s; red[wv*2+1] = s2; }
  __syncthreads();
  if (tid == 0) {
    float ts = 0.f, ts2 = 0.f;
    #pragma unroll
    for (int i = 0; i < 4; ++i) { ts += red[i*2]; ts2 += red[i*2+1]; }
    red[0] = ts; red[1] = ts2;
  }
  __syncthreads();
  float mu  = red[0] * (1.f / DMODEL);
  float var = red[1] * (1.f / DMODEL) - mu * mu;
  float rs  = rsqrtf(var + 1e-5f);
  float4 wv4 = ((const float4*)w)[tid];
  float4 bv4 = ((const float4*)b)[tid];
  float o[4];
  o[0] = (v.x - mu) * rs * wv4.x + bv4.x;
  o[1] = (v.y - mu) * rs * wv4.y + bv4.y;
  o[2] = (v.z - mu) * rs * wv4.z + bv4.z;
  o[3] = (v.w - mu) * rs * wv4.w + bv4.w;
  ushort4 h, l;
  split4(o, &h, &l);
  *(ushort4*)&xnhi[(size_t)row * DMODEL + tid * 4] = h;
  *(ushort4*)&xnlo[(size_t)row * DMODEL + tid * 4] = l;
}

// ---------------- weight split: fp32 -> (hi, lo) bf16 planes ----------------
__global__ __launch_bounds__(256) void wsplit_kernel(
    const float* __restrict__ W, ushort* __restrict__ Whi,
    ushort* __restrict__ Wlo, int n4)
{
  int i = blockIdx.x * 256 + threadIdx.x;
  if (i >= n4) return;
  float4 v = ((const float4*)W)[i];
  ushort4 h, l;
  split4((const float*)&v, &h, &l);
  ((ushort4*)Whi)[i] = h;
  ((ushort4*)Wlo)[i] = l;
}

// ---------------- split-plane bf16 MFMA GEMM (planes fused in K-loop) ------
// C[M,N] = Ahi*Bhi^T + Alo*Bhi^T + Ahi*Blo^T (+bias)(+res); fp32-class (~1e-5).
// 128x128 tile, BK=32, 256 thr (4 waves, 64x64 quadrant each, 4x4 16x16x32
// frags), global_load_lds 16B into linear LDS, 2 barriers per K-step.
// ldA/ldB: row strides in ushorts (rows may be embedded in a wider buffer).
template<bool ADD_RES>
__global__ __launch_bounds__(256) void gemm_mfma_split(
    const ushort* __restrict__ Ahi, const ushort* __restrict__ Alo, int ldA,
    const ushort* __restrict__ Bhi, const ushort* __restrict__ Blo, int ldB,
    const float* __restrict__ bias, const float* __restrict__ res,
    float* __restrict__ C, int M, int N, int K)
{
  __shared__ __align__(16) ushort AlsH[128 * 32];
  __shared__ __align__(16) ushort AlsL[128 * 32];
  __shared__ __align__(16) ushort BlsH[128 * 32];
  __shared__ __align__(16) ushort BlsL[128 * 32];
  int tid  = threadIdx.x;
  int lane = tid & 63;
  int w    = tid >> 6;
  int n0 = blockIdx.x * 128;
  int m0 = blockIdx.y * 128;
  int wr = (w >> 1) * 64;
  int wc = (w & 1) * 64;
  // staging: chunk-block cb = 16 LDS rows; lane l -> row cb*16+(l>>2),
  // k-chunk (l&3)*8 ushorts (16B). HW writes LDS at base + l*16B (linear):
  // lds ushort off = cb*512 + 8*l = (cb*16 + (l>>2))*32 + (l&3)*8. Matches.
  int cb0  = w * 2;
  int srow = lane >> 2;
  int skc  = (lane & 3) * 8;
  int fr = lane & 15;           // fragment row/col (lane&15)
  int kg = lane >> 4;           // k-group: k = kg*8..+8

  f32x4_t acc[4][4];
  #pragma unroll
  for (int i = 0; i < 4; ++i)
    #pragma unroll
    for (int j = 0; j < 4; ++j)
      acc[i][j] = (f32x4_t){0.f, 0.f, 0.f, 0.f};

  for (int kk = 0; kk < K; kk += 32) {
    #pragma unroll
    for (int c = 0; c < 2; ++c) {
      int cb = cb0 + c;
      int row = cb * 16 + srow;
      size_t ga = (size_t)(m0 + row) * ldA + kk + skc;
      size_t gb = (size_t)(n0 + row) * ldB + kk + skc;
      __builtin_amdgcn_global_load_lds(
          (const __attribute__((address_space(1))) uint32_t*)(Ahi + ga),
          (__attribute__((address_space(3))) uint32_t*)(AlsH + cb * 512), 16, 0, 0);
      __builtin_amdgcn_global_load_lds(
          (const __attribute__((address_space(1))) uint32_t*)(Alo + ga),
          (__attribute__((address_space(3))) uint32_t*)(AlsL + cb * 512), 16, 0, 0);
      __builtin_amdgcn_global_load_lds(
          (const __attribute__((address_space(1))) uint32_t*)(Bhi + gb),
          (__attribute__((address_space(3))) uint32_t*)(BlsH + cb * 512), 16, 0, 0);
      __builtin_amdgcn_global_load_lds(
          (const __attribute__((address_space(1))) uint32_t*)(Blo + gb),
          (__attribute__((address_space(3))) uint32_t*)(BlsL + cb * 512), 16, 0, 0);
    }
    __syncthreads();
    bf16x8_t ah[4], al[4], bh[4], bl[4];
    #pragma unroll
    for (int i = 0; i < 4; ++i) {
      int ro = (wr + i * 16 + fr) * 32 + kg * 8;
      ah[i] = *(const bf16x8_t*)&AlsH[ro];
      al[i] = *(const bf16x8_t*)&AlsL[ro];
    }
    #pragma unroll
    for (int j = 0; j < 4; ++j) {
      int ro = (wc + j * 16 + fr) * 32 + kg * 8;
      bh[j] = *(const bf16x8_t*)&BlsH[ro];
      bl[j] = *(const bf16x8_t*)&BlsL[ro];
    }
    #pragma unroll
    for (int i = 0; i < 4; ++i)
      #pragma unroll
      for (int j = 0; j < 4; ++j) {
        acc[i][j] = __builtin_amdgcn_mfma_f32_16x16x32_bf16(ah[i], bh[j], acc[i][j], 0, 0, 0);
        acc[i][j] = __builtin_amdgcn_mfma_f32_16x16x32_bf16(al[i], bh[j], acc[i][j], 0, 0, 0);
        acc[i][j] = __builtin_amdgcn_mfma_f32_16x16x32_bf16(ah[i], bl[j], acc[i][j], 0, 0, 0);
      }
    __syncthreads();
  }
  // epilogue: D mapping col=lane&15, row=(lane>>4)*4+e  [m89/m91-verified]
  #pragma unroll
  for (int i = 0; i < 4; ++i) {
    #pragma unroll
    for (int j = 0; j < 4; ++j) {
      int n = n0 + wc + j * 16 + fr;
      float bv = bias[n];
      #pragma unroll
      for (int e = 0; e < 4; ++e) {
        size_t m = (size_t)m0 + wr + i * 16 + kg * 4 + e;
        float v = acc[i][j][e] + bv;
        if (ADD_RES) v += res[m * N + n];
        C[m * N + n] = v;
      }
    }
  }
}

// ---------------- causal depthwise conv (D_CONV=4) + SiLU ----------------
__global__ __launch_bounds__(256) void conv_silu_kernel(
    const float* __restrict__ xz, const float* __restrict__ cw,
    const float* __restrict__ cb, float* __restrict__ xc)
{
  int idx = blockIdx.x * 256 + threadIdx.x;   // m*512 + d4
  int m = idx >> 9;
  int d = (idx & 511) * 4;
  int t = m & (LSEQ - 1);
  const float* base = xz + (size_t)m * (2 * DINNER) + d;
  float w[4][4];
  #pragma unroll
  for (int i = 0; i < 4; ++i) {
    float4 wv = ((const float4*)cw)[d + i];
    w[i][0] = wv.x; w[i][1] = wv.y; w[i][2] = wv.z; w[i][3] = wv.w;
  }
  float4 cbv = *(const float4*)(cb + d);
  float a[4] = {cbv.x, cbv.y, cbv.z, cbv.w};
  #pragma unroll
  for (int j = 0; j < 4; ++j) {
    int tt = t - 3 + j;
    if (tt >= 0) {
      float4 xv = *(const float4*)(base + ((ptrdiff_t)j - 3) * (2 * DINNER));
      a[0] = fmaf(xv.x, w[0][j], a[0]);
      a[1] = fmaf(xv.y, w[1][j], a[1]);
      a[2] = fmaf(xv.z, w[2][j], a[2]);
      a[3] = fmaf(xv.w, w[3][j], a[3]);
    }
  }
  float4 o;
  o.x = silu_f(a[0]); o.y = silu_f(a[1]); o.z = silu_f(a[2]); o.w = silu_f(a[3]);
  *(float4*)&xc[(size_t)m * DINNER + d] = o;
}

// ---------------- proj = xc @ W_x^T : [M, 96], K = 2048 ----------------
__global__ __launch_bounds__(256) void proj_gemm_kernel(
    const float* __restrict__ xc, const float* __restrict__ Wx,
    float* __restrict__ proj)
{
  __shared__ float As[32][68];
  __shared__ float Bs[32][100];
  int tid = threadIdx.x;
  int m0 = blockIdx.x * 64;
  int r  = tid >> 3;
  int c4 = (tid & 7) * 4;
  const float* Ap = xc + (size_t)(m0 + r) * DINNER + c4;
  const float* Bp = Wx + (size_t)r * DINNER + c4;
  int tx = (tid & 15) * 6;
  int ty = (tid >> 4) * 4;
  float acc[4][6] = {};
  for (int k0 = 0; k0 < DINNER; k0 += 32) {
    float4 a0 = *(const float4*)(Ap + k0);
    float4 a1 = *(const float4*)(Ap + k0 + (size_t)32 * DINNER);
    float4 b0 = *(const float4*)(Bp + k0);
    float4 b1 = *(const float4*)(Bp + k0 + (size_t)32 * DINNER);
    float4 b2 = *(const float4*)(Bp + k0 + (size_t)64 * DINNER);
    __syncthreads();
    const float* a0f = (const float*)&a0;
    const float* a1f = (const float*)&a1;
    const float* b0f = (const float*)&b0;
    const float* b1f = (const float*)&b1;
    const float* b2f = (const float*)&b2;
    #pragma unroll
    for (int j = 0; j < 4; ++j) {
      As[c4 + j][r]      = a0f[j];
      As[c4 + j][r + 32] = a1f[j];
      Bs[c4 + j][r]      = b0f[j];
      Bs[c4 + j][r + 32] = b1f[j];
      Bs[c4 + j][r + 64] = b2f[j];
    }
    __syncthreads();
    #pragma unroll
    for (int k = 0; k < 32; ++k) {
      float4 av = *(const float4*)&As[k][ty];
      const float* af = (const float*)&av;
      float bvv[6];
      #pragma unroll
      for (int j = 0; j < 6; ++j) bvv[j] = Bs[k][tx + j];
      #pragma unroll
      for (int i = 0; i < 4; ++i)
        #pragma unroll
        for (int j = 0; j < 6; ++j)
          acc[i][j] = fmaf(af[i], bvv[j], acc[i][j]);
    }
  }
  #pragma unroll
  for (int i = 0; i < 4; ++i) {
    size_t off = (size_t)(m0 + ty + i) * NPROJ + tx;
    #pragma unroll
    for (int j = 0; j < 6; ++j) proj[off + j] = acc[i][j];
  }
}

// ---------------- selective scan (dt fused) + skip + gating -> y planes ----
// Block: 256 thr = 16 channels x 16 states; grid (DINNER/16, NB).
// delta computed in-block from proj[:, :64] @ W_dt^T (no 64MB delta buffer).
// Gated y written as split-bf16 planes into the dead x_in columns of xz:
// per row, ushorts [0,2048) = yhi, [2048,4096) = ylo (z cols untouched).
#define TCH 64
__global__ __launch_bounds__(256) void scan_kernel(
    float* __restrict__ xz, const float* __restrict__ xc,
    const float* __restrict__ proj,
    const float* __restrict__ Wdt, const float* __restrict__ bdt,
    const float* __restrict__ A_log, const float* __restrict__ Dp)
{
  __shared__ float wdt_s[16][65];
  __shared__ float bdt_s[16];
  __shared__ float ps[TCH][65];
  __shared__ float del_s[TCH][17];
  __shared__ float xcs[TCH][16];
  __shared__ float zs[TCH][16];
  __shared__ float bcs[TCH][32];
  __shared__ float ys[TCH][16];
  int tid = threadIdx.x;
  int b   = blockIdx.y;
  int d0  = blockIdx.x * 16;
  int dl  = tid >> 4;
  int s   = tid & 15;
  int d   = d0 + dl;
  float Areg = -expf(A_log[(size_t)d * DSTATE + s]);
  float Dd   = Dp[d];
  float h = 0.f;
  // stage W_dt rows [d0, d0+16) and b_dt once
  {
    int rr = tid >> 4;
    int k4 = (tid & 15) * 4;
    float4 wv = *(const float4*)&Wdt[(size_t)(d0 + rr) * DTRANK + k4];
    wdt_s[rr][k4+0] = wv.x; wdt_s[rr][k4+1] = wv.y;
    wdt_s[rr][k4+2] = wv.z; wdt_s[rr][k4+3] = wv.w;
    if (tid < 16) bdt_s[tid] = bdt[d0 + tid];
  }
  int row  = tid >> 2, cc  = (tid & 3) * 4;   // 64x16 staging
  int row2 = tid >> 3, cc2 = (tid & 7) * 4;   // 64x32 staging
  int g    = tid >> 6;                        // delta d-group 0..3
  int tt   = tid & 63;                        // delta t-index
  ushort* yw = (ushort*)xz;
  for (int t0 = 0; t0 < LSEQ; t0 += TCH) {
    size_t mbase = (size_t)b * LSEQ + t0;
    {
      const float* pr = &proj[(mbase + row) * NPROJ];
      int q = tid & 3;
      #pragma unroll
      for (int jj = 0; jj < 4; ++jj) {
        float4 v = *(const float4*)&pr[q * 16 + jj * 4];
        ps[row][q*16 + jj*4 + 0] = v.x;
        ps[row][q*16 + jj*4 + 1] = v.y;
        ps[row][q*16 + jj*4 + 2] = v.z;
        ps[row][q*16 + jj*4 + 3] = v.w;
      }
    }
    *(float4*)&xcs[row][cc] = *(const float4*)&xc[(mbase + row) * DINNER + d0 + cc];
    *(float4*)&zs[row][cc]  = *(const float4*)&xz[(mbase + row) * (2*DINNER) + DINNER + d0 + cc];
    *(float4*)&bcs[row2][cc2]      = *(const float4*)&proj[(mbase + row2) * NPROJ + DTRANK + cc2];
    *(float4*)&bcs[row2 + 32][cc2] = *(const float4*)&proj[(mbase + row2 + 32) * NPROJ + DTRANK + cc2];
    __syncthreads();
    // delta: thread (g, tt) -> del_s[tt][g*4 + j], j=0..3
    {
      float a0 = 0.f, a1 = 0.f, a2 = 0.f, a3 = 0.f;
      #pragma unroll 8
      for (int k = 0; k < DTRANK; ++k) {
        float p = ps[tt][k];
        a0 = fmaf(p, wdt_s[g*4+0][k], a0);
        a1 = fmaf(p, wdt_s[g*4+1][k], a1);
        a2 = fmaf(p, wdt_s[g*4+2][k], a2);
        a3 = fmaf(p, wdt_s[g*4+3][k], a3);
      }
      float vv[4] = {a0, a1, a2, a3};
      #pragma unroll
      for (int j = 0; j < 4; ++j) {
        float v = vv[j] + bdt_s[g*4+j];
        v = (v > 20.f) ? v : log1pf(expf(v));
        del_s[tt][g*4+j] = v;
      }
    }
    __syncthreads();
    for (int t = 0; t < TCH; ++t) {
      float dlt = del_s[t][dl];
      float xv  = xcs[t][dl];
      float bv  = bcs[t][s];
      float cv  = bcs[t][16 + s];
      float dA  = __expf(dlt * Areg);
      h = fmaf(dA, h, dlt * xv * bv);
      float p = h * cv;
      p += __shfl_xor(p, 1, 16);
      p += __shfl_xor(p, 2, 16);
      p += __shfl_xor(p, 4, 16);
      p += __shfl_xor(p, 8, 16);
      if (s == 0) {
        float zv = zs[t][dl];
        ys[t][dl] = (p + xv * Dd) * (zv / (1.f + __expf(-zv)));
      }
    }
    __syncthreads();
    {
      float4 yv = *(float4*)&ys[row][cc];
      ushort4 hh, ll;
      split4((const float*)&yv, &hh, &ll);
      size_t rb = (mbase + row) * (size_t)(4 * DINNER);   // row stride 8192 ushorts
      *(ushort4*)&yw[rb + d0 + cc] = hh;
      *(ushort4*)&yw[rb + DINNER + d0 + cc] = ll;
    }
    __syncthreads();
  }
}

// ---------------- launch ----------------
extern "C" void kernel_launch(void* const* d_in, const int* in_sizes, int n_in,
                              void* d_out, int out_size, void* d_ws, size_t ws_size,
                              hipStream_t stream)
{
  const float* x      = (const float*)d_in[0];
  const float* ln_w   = (const float*)d_in[1];
  const float* ln_b   = (const float*)d_in[2];
  const float* W_in   = (const float*)d_in[3];
  const float* b_in   = (const float*)d_in[4];
  const float* conv_w = (const float*)d_in[5];
  const float* conv_b = (const float*)d_in[6];
  const float* W_x    = (const float*)d_in[7];
  const float* W_dt   = (const float*)d_in[8];
  const float* b_dt   = (const float*)d_in[9];
  const float* A_log  = (const float*)d_in[10];
  const float* Dp     = (const float*)d_in[11];
  const float* W_out  = (const float*)d_in[12];
  const float* b_out  = (const float*)d_in[13];
  float* out = (float*)d_out;

  // ws-size diagnostic: if scratch is too small, emit unambiguous sentinel
  // (absmax ~1e30) instead of faulting. ws_size is constant -> graph-safe.
  if (ws_size < WS_REQUIRED) {
    poison_kernel<<<4, 256, 0, stream>>>(out);
    return;
  }

  // d_out doubles as scratch for xn planes (fully overwritten by final GEMM).
  ushort* xnhi = (ushort*)d_out;                       // 16 MB
  ushort* xnlo = xnhi + (size_t)MROWS * DMODEL;        // 16 MB

  // workspace layout (bytes), total 229,638,144 (~219 MB)
  uint8_t* w8  = (uint8_t*)d_ws;
  float* xz    = (float*)(w8);                         // 134,217,728 (x_in|z; x_in cols reused for y planes)
  float* xc    = (float*)(w8 + 134217728);             //  67,108,864
  float* proj  = (float*)(w8 + 201326592);             //   3,145,728
  ushort* Winhi= (ushort*)(w8 + 204472320);            //   8,388,608
  ushort* Winlo= (ushort*)(w8 + 212860928);            //   8,388,608
  ushort* Wohi = (ushort*)(w8 + 221249536);            //   4,194,304
  ushort* Wolo = (ushort*)(w8 + 225443840);            //   4,194,304

  wsplit_kernel<<<(2 * DINNER * DMODEL / 4 + 255) / 256, 256, 0, stream>>>(
      W_in, Winhi, Winlo, 2 * DINNER * DMODEL / 4);
  wsplit_kernel<<<(DMODEL * DINNER / 4 + 255) / 256, 256, 0, stream>>>(
      W_out, Wohi, Wolo, DMODEL * DINNER / 4);

  ln_split_kernel<<<MROWS, 256, 0, stream>>>(x, ln_w, ln_b, xnhi, xnlo);

  gemm_mfma_split<false><<<dim3(2 * DINNER / 128, MROWS / 128), 256, 0, stream>>>(
      xnhi, xnlo, DMODEL, Winhi, Winlo, DMODEL, b_in, nullptr,
      xz, MROWS, 2 * DINNER, DMODEL);

  conv_silu_kernel<<<(MROWS * DINNER / 4) / 256, 256, 0, stream>>>(xz, conv_w, conv_b, xc);

  proj_gemm_kernel<<<MROWS / 64, 256, 0, stream>>>(xc, W_x, proj);

  scan_kernel<<<dim3(DINNER / 16, NB), 256, 0, stream>>>(
      xz, xc, proj, W_dt, b_dt, A_log, Dp);

  gemm_mfma_split<true><<<dim3(DMODEL / 128, MROWS / 128), 256, 0, stream>>>(
      (const ushort*)xz, (const ushort*)xz + DINNER, 4 * DINNER,
      Wohi, Wolo, DINNER, b_out, x, out, MROWS, DMODEL, DINNER);
}